// Round 6
// baseline (1630.492 us; speedup 1.0000x reference)
//
#include <hip/hip_runtime.h>
#include <cstdint>

#define ALPHA 0.2f

constexpr int NB = 8;
constexpr int NN = 2048;
constexpr int NF = 256;

__device__ __forceinline__ float bf2f(unsigned short u) {
    union { unsigned int i; float f; } v;
    v.i = ((unsigned int)u) << 16;
    return v.f;
}
__device__ __forceinline__ unsigned short f2bf(float f) {
    union { float f; unsigned int i; } v;
    v.f = f;
    v.i += 0x7fffu + ((v.i >> 16) & 1);  // round-to-nearest-even
    return (unsigned short)(v.i >> 16);
}

// ---------------------------------------------------------------------------
// Kernel 1: Wh = h @ W (M=16384, K=256, N=256). fp32 in, fp32 acc, bf16 out
// (scratch). 64x64 tile/block; 256 threads as 16(tx=col)x16(ty=row), 4x4 each.
// ---------------------------------------------------------------------------
__global__ __launch_bounds__(256, 2) void k_wh(const float* __restrict__ h,
                                               const float* __restrict__ W,
                                               unsigned short* __restrict__ Wh) {
    __shared__ __align__(16) float As[64][68];  // [row][k], 272B stride
    __shared__ __align__(16) float Bs[64][68];  // [k][col]
    const int tid = threadIdx.x;
    const int tx = tid & 15;   // cols tx*4 .. tx*4+3  (of 64)
    const int ty = tid >> 4;   // rows ty*4 .. ty*4+3  (of 64)
    const int row0 = (blockIdx.x >> 2) * 64;
    const int col0 = (blockIdx.x & 3) * 64;

    float acc[4][4];
#pragma unroll
    for (int i = 0; i < 4; ++i)
#pragma unroll
        for (int j = 0; j < 4; ++j) acc[i][j] = 0.f;

    for (int k0 = 0; k0 < NF; k0 += 64) {
#pragma unroll
        for (int it = 0; it < 4; ++it) {
            const int q = tid + it * 256;   // 0..1023
            const int r = q >> 4;           // 0..63
            const int c4 = (q & 15) * 4;    // 0..60
            *(float4*)&As[r][c4] =
                *(const float4*)&h[(size_t)(row0 + r) * NF + k0 + c4];
            *(float4*)&Bs[r][c4] =
                *(const float4*)&W[(size_t)(k0 + r) * NF + col0 + c4];
        }
        __syncthreads();
#pragma unroll
        for (int kk = 0; kk < 64; kk += 4) {
            float4 b4[4];
#pragma unroll
            for (int e = 0; e < 4; ++e) b4[e] = *(const float4*)&Bs[kk + e][tx * 4];
#pragma unroll
            for (int i = 0; i < 4; ++i) {
                const float4 a4 = *(const float4*)&As[ty * 4 + i][kk];
                const float* ap = (const float*)&a4;
#pragma unroll
                for (int e = 0; e < 4; ++e) {
                    const float s = ap[e];
                    const float* bp = (const float*)&b4[e];
                    acc[i][0] += s * bp[0];
                    acc[i][1] += s * bp[1];
                    acc[i][2] += s * bp[2];
                    acc[i][3] += s * bp[3];
                }
            }
        }
        __syncthreads();
    }
#pragma unroll
    for (int i = 0; i < 4; ++i) {
        ushort4 o;
        o.x = f2bf(acc[i][0]);
        o.y = f2bf(acc[i][1]);
        o.z = f2bf(acc[i][2]);
        o.w = f2bf(acc[i][3]);
        *(ushort4*)&Wh[(size_t)(row0 + ty * 4 + i) * NF + col0 + tx * 4] = o;
    }
}

// ---------------------------------------------------------------------------
// Kernel S: s1/s2 row dots. One wave per row. Wh bf16 scratch, a fp32 input.
// ---------------------------------------------------------------------------
__global__ __launch_bounds__(256) void k_s12(const unsigned short* __restrict__ Wh,
                                             const float* __restrict__ a,
                                             float* __restrict__ s1,
                                             float* __restrict__ s2) {
    const int tid = threadIdx.x;
    const int lane = tid & 63;
    const int row = blockIdx.x * 4 + (tid >> 6);
    uint2 uw = *(const uint2*)&Wh[(size_t)row * NF + lane * 4];
    const float4 a1 = *(const float4*)&a[lane * 4];
    const float4 a2 = *(const float4*)&a[NF + lane * 4];
    const unsigned short* pw = (const unsigned short*)&uw;
    const float* p1 = (const float*)&a1;
    const float* p2 = (const float*)&a2;
    float s1v = 0.f, s2v = 0.f;
#pragma unroll
    for (int e = 0; e < 4; ++e) {
        const float v = bf2f(pw[e]);
        s1v += v * p1[e];
        s2v += v * p2[e];
    }
#pragma unroll
    for (int m = 32; m >= 1; m >>= 1) {
        s1v += __shfl_xor(s1v, m);
        s2v += __shfl_xor(s2v, m);
    }
    if (lane == 0) {
        s1[row] = s1v;
        s2[row] = s2v;
    }
}

// ---------------------------------------------------------------------------
// Kernel 2: fused masked softmax + attn @ Wh.
// Block = 64 rows x 256 f (grid 256). j in tiles of 32:
//  - stage Wh j-tile as bf16 in LDS (16 KB)
//  - P[ir][kk] = adj ? exp(leaky(s1+s2)) : 0 into Ps (fp32); denominator via
//    32-lane shuffle reduce, unique writer per ir
//  - 8x8 per-thread register tile FMA (tx = f-octet of 32, ty = row-octet of 8)
// No max-subtraction: |logit| <~ 6 here, exp is safe in fp32.
// ---------------------------------------------------------------------------
__global__ __launch_bounds__(256, 2) void k_attn(const unsigned short* __restrict__ Wh,
                                                 const int* __restrict__ adj,
                                                 const float* __restrict__ s1g,
                                                 const float* __restrict__ s2g,
                                                 float* __restrict__ out) {
    __shared__ __align__(16) unsigned short Whs[32][256];  // bf16, 512B stride
    __shared__ __align__(16) float Ps[64][40];             // 160B stride
    __shared__ float s1_s[64];
    __shared__ float l_s[64];

    const int tid = threadIdx.x;
    const int tx = tid & 31;   // f octet: f = tx*8 .. tx*8+7
    const int ty = tid >> 5;   // row octet: rows ty*8 .. ty*8+7
    const int bb = blockIdx.x >> 5;          // batch 0..7
    const int i0 = (blockIdx.x & 31) * 64;   // row tile start

    if (tid < 64) {
        s1_s[tid] = s1g[bb * NN + i0 + tid];
        l_s[tid] = 0.f;
    }
    __syncthreads();

    float acc[8][8];
#pragma unroll
    for (int i = 0; i < 8; ++i)
#pragma unroll
        for (int j = 0; j < 8; ++j) acc[i][j] = 0.f;

    const size_t whBase = (size_t)bb * NN * NF;
    const size_t adjBase = (size_t)bb * NN * NN;

    for (int j0 = 0; j0 < NN; j0 += 32) {
        // ---- stage Wh j-tile (32 x 256 bf16) as uint4 (8 bf16 each) ----
#pragma unroll
        for (int it = 0; it < 4; ++it) {
            const int q = tid + it * 256;   // 0..1023
            const int kk = q >> 5;          // 0..31
            const int c8 = (q & 31) * 8;    // 0..248
            *(uint4*)&Whs[kk][c8] =
                *(const uint4*)&Wh[whBase + (size_t)(j0 + kk) * NF + c8];
        }
        // ---- P tile: 64 ir x 32 kk, 8 per thread ----
#pragma unroll
        for (int it = 0; it < 8; ++it) {
            const int q = tid + it * 256;   // 0..2047
            const int kk = q & 31;
            const int ir = q >> 5;          // constant per 32-lane half
            const int j = j0 + kk;
            const int av = adj[adjBase + (size_t)(i0 + ir) * NN + j];
            const float x = s1_s[ir] + s2g[bb * NN + j];
            const float e = x > 0.f ? x : ALPHA * x;
            const float p = av > 0 ? __expf(e) : 0.f;
            Ps[ir][kk] = p;
            float ps = p;
            ps += __shfl_xor(ps, 16);
            ps += __shfl_xor(ps, 8);
            ps += __shfl_xor(ps, 4);
            ps += __shfl_xor(ps, 2);
            ps += __shfl_xor(ps, 1);
            if ((tid & 31) == 0) l_s[ir] += ps;  // unique (thread,it) per ir
        }
        __syncthreads();
        // ---- FMA: acc[ii][f] += P[ty*8+ii][kk] * Wh[kk][tx*8+f] ----
#pragma unroll
        for (int kk = 0; kk < 32; kk += 4) {
            float w[4][8];
#pragma unroll
            for (int e = 0; e < 4; ++e) {
                uint4 uw = *(const uint4*)&Whs[kk + e][tx * 8];
                const unsigned short* pw = (const unsigned short*)&uw;
#pragma unroll
                for (int f = 0; f < 8; ++f) w[e][f] = bf2f(pw[f]);
            }
#pragma unroll
            for (int ii = 0; ii < 8; ++ii) {
                const float4 p4 = *(const float4*)&Ps[ty * 8 + ii][kk];
                const float* pp = (const float*)&p4;
#pragma unroll
                for (int e = 0; e < 4; ++e) {
                    const float s = pp[e];
#pragma unroll
                    for (int f = 0; f < 8; ++f) acc[ii][f] += s * w[e][f];
                }
            }
        }
        __syncthreads();
    }

    // ---- epilogue: divide by denominator, fp32 store ----
#pragma unroll
    for (int ii = 0; ii < 8; ++ii) {
        const float inv = 1.0f / l_s[ty * 8 + ii];
        float4 o0, o1;
        o0.x = acc[ii][0] * inv; o0.y = acc[ii][1] * inv;
        o0.z = acc[ii][2] * inv; o0.w = acc[ii][3] * inv;
        o1.x = acc[ii][4] * inv; o1.y = acc[ii][5] * inv;
        o1.z = acc[ii][6] * inv; o1.w = acc[ii][7] * inv;
        float* dst = &out[((size_t)bb * NN + i0 + ty * 8 + ii) * NF + tx * 8];
        *(float4*)dst = o0;
        *(float4*)(dst + 4) = o1;
    }
}

// ---------------------------------------------------------------------------
extern "C" void kernel_launch(void* const* d_in, const int* in_sizes, int n_in,
                              void* d_out, int out_size, void* d_ws, size_t ws_size,
                              hipStream_t stream) {
    const float* h = (const float*)d_in[0];
    const int* adj = (const int*)d_in[1];
    const float* W = (const float*)d_in[2];
    const float* a = (const float*)d_in[3];
    float* out = (float*)d_out;

    unsigned short* Wh = (unsigned short*)d_ws;  // 8.4 MB bf16 scratch
    float* s1 = (float*)((char*)d_ws + (size_t)NB * NN * NF * sizeof(unsigned short));
    float* s2 = s1 + (size_t)NB * NN;

    k_wh<<<dim3((NB * NN / 64) * (NF / 64)), dim3(256), 0, stream>>>(h, W, Wh);
    k_s12<<<dim3(NB * NN / 4), dim3(256), 0, stream>>>(Wh, a, s1, s2);
    k_attn<<<dim3(NB * (NN / 64)), dim3(256), 0, stream>>>(Wh, adj, s1, s2, out);
}

// Round 8
// 377.918 us; speedup vs baseline: 4.3144x; 4.3144x over previous
//
#include <hip/hip_runtime.h>
#include <cstdint>

#define ALPHA 0.2f

constexpr int NB = 8;
constexpr int NN = 2048;
constexpr int NF = 256;

typedef __attribute__((ext_vector_type(8))) short bf16x8;
typedef __attribute__((ext_vector_type(4))) float f32x4;

__device__ __forceinline__ float bf2f(unsigned short u) {
    union { unsigned int i; float f; } v;
    v.i = ((unsigned int)u) << 16;
    return v.f;
}
__device__ __forceinline__ unsigned short f2bf(float f) {
    union { float f; unsigned int i; } v;
    v.f = f;
    v.i += 0x7fffu + ((v.i >> 16) & 1);  // round-to-nearest-even
    return (unsigned short)(v.i >> 16);
}

// ---------------------------------------------------------------------------
// Kernel 1: Wh = h @ W (M=16384, K=256, N=256), fp32 VALU, output written as
// TRANSPOSED bf16 scratch Wh_T[b][f][n] (f-major) so k_attn's MFMA B-operand
// reads are contiguous. 64x64 tile/block; 16x16 threads, 4x4 each.
// ---------------------------------------------------------------------------
__global__ __launch_bounds__(256, 2) void k_wh(const float* __restrict__ h,
                                               const float* __restrict__ W,
                                               unsigned short* __restrict__ WhT) {
    __shared__ __align__(16) float As[64][68];  // [row][k]
    __shared__ __align__(16) float Bs[64][68];  // [k][col]
    const int tid = threadIdx.x;
    const int tx = tid & 15;   // cols tx*4 .. +3 (of 64)
    const int ty = tid >> 4;   // rows ty*4 .. +3 (of 64)
    const int row0 = (blockIdx.x >> 2) * 64;   // global row (0..16383), 64-mult
    const int col0 = (blockIdx.x & 3) * 64;    // f (0..255)
    const int bb = row0 >> 11;                 // batch (tile never straddles)
    const int n0 = row0 & (NN - 1);            // n within batch

    float acc[4][4];
#pragma unroll
    for (int i = 0; i < 4; ++i)
#pragma unroll
        for (int j = 0; j < 4; ++j) acc[i][j] = 0.f;

    for (int k0 = 0; k0 < NF; k0 += 64) {
#pragma unroll
        for (int it = 0; it < 4; ++it) {
            const int q = tid + it * 256;   // 0..1023
            const int r = q >> 4;           // 0..63
            const int c4 = (q & 15) * 4;    // 0..60
            *(float4*)&As[r][c4] =
                *(const float4*)&h[(size_t)(row0 + r) * NF + k0 + c4];
            *(float4*)&Bs[r][c4] =
                *(const float4*)&W[(size_t)(k0 + r) * NF + col0 + c4];
        }
        __syncthreads();
#pragma unroll
        for (int kk = 0; kk < 64; kk += 4) {
            float4 b4[4];
#pragma unroll
            for (int e = 0; e < 4; ++e) b4[e] = *(const float4*)&Bs[kk + e][tx * 4];
#pragma unroll
            for (int i = 0; i < 4; ++i) {
                const float4 a4 = *(const float4*)&As[ty * 4 + i][kk];
                const float* ap = (const float*)&a4;
#pragma unroll
                for (int e = 0; e < 4; ++e) {
                    const float s = ap[e];
                    const float* bp = (const float*)&b4[e];
                    acc[i][0] += s * bp[0];
                    acc[i][1] += s * bp[1];
                    acc[i][2] += s * bp[2];
                    acc[i][3] += s * bp[3];
                }
            }
        }
        __syncthreads();
    }
    // transposed store: for each col f, 4 consecutive n per thread -> ushort4
#pragma unroll
    for (int j = 0; j < 4; ++j) {
        ushort4 o;
        o.x = f2bf(acc[0][j]);
        o.y = f2bf(acc[1][j]);
        o.z = f2bf(acc[2][j]);
        o.w = f2bf(acc[3][j]);
        const size_t f = col0 + tx * 4 + j;
        *(ushort4*)&WhT[((size_t)bb * NF + f) * NN + n0 + ty * 4] = o;
    }
}

// ---------------------------------------------------------------------------
// Kernel S: s1[n] = sum_f WhT[b][f][n]*a1[f]; s2 likewise. 256 n per block.
// Coalesced along n; a[] loads are wave-uniform (scalar).
// ---------------------------------------------------------------------------
__global__ __launch_bounds__(256) void k_s12(const unsigned short* __restrict__ WhT,
                                             const float* __restrict__ a,
                                             float* __restrict__ s1,
                                             float* __restrict__ s2) {
    const int tid = threadIdx.x;
    const int bb = blockIdx.x >> 3;
    const int n = (blockIdx.x & 7) * 256 + tid;
    const unsigned short* base = WhT + (size_t)bb * NF * NN + n;
    float s1v = 0.f, s2v = 0.f;
#pragma unroll 4
    for (int f = 0; f < NF; ++f) {
        const float v = bf2f(base[(size_t)f * NN]);
        s1v += v * a[f];
        s2v += v * a[NF + f];
    }
    s1[bb * NN + n] = s1v;
    s2[bb * NN + n] = s2v;
}

// ---------------------------------------------------------------------------
// Kernel 2: fused masked softmax + attn @ Wh, MFMA version.
// Block = 32 q-rows x 256 f, one batch; grid 512 (2 blocks/CU, 8 waves/CU).
// Per j-tile of 64:
//   - stage WhT[f][j-tile] (256x64 bf16) into LDS (B-operand, k-contiguous)
//   - compute P = adj ? exp(leaky(s1+s2)) : 0 (fp32), row-sum into l_s via
//     32-lane xor-shuffle (unique writer per row), pack bf16 pairs into Pb
//   - 2x4 tiles of v_mfma_f32_16x16x32_bf16 per wave (wave owns 64 f)
// Epilogue: scale by 1/l, fp32 store.
// Verified layouts: A[m=lane&15][k=(lane>>4)*8+j]; C/D col=lane&15,
// row=(lane>>4)*4+reg.
// ---------------------------------------------------------------------------
__global__ __launch_bounds__(256, 2) void k_attn(const unsigned short* __restrict__ WhT,
                                                 const int* __restrict__ adj,
                                                 const float* __restrict__ s1g,
                                                 const float* __restrict__ s2g,
                                                 float* __restrict__ out) {
    __shared__ __align__(16) unsigned short WhsT[256][72];  // [f][k], pad->144B
    __shared__ __align__(16) unsigned short Pb[32][72];     // [i][k] bf16
    __shared__ float s1_s[32];
    __shared__ float l_s[32];

    const int tid = threadIdx.x;
    const int lane = tid & 63;
    const int l16 = lane & 15;
    const int quad = lane >> 4;
    const int wave = tid >> 6;       // 0..3 -> f slice wave*64
    const int bb = blockIdx.x >> 6;          // batch
    const int i0 = (blockIdx.x & 63) * 32;   // q-row tile start

    if (tid < 32) {
        s1_s[tid] = s1g[bb * NN + i0 + tid];
        l_s[tid] = 0.f;
    }
    __syncthreads();

    f32x4 acc[2][4];
#pragma unroll
    for (int m = 0; m < 2; ++m)
#pragma unroll
        for (int nf = 0; nf < 4; ++nf) acc[m][nf] = (f32x4){0.f, 0.f, 0.f, 0.f};

    const size_t whtBase = (size_t)bb * NF * NN;
    const size_t adjBase = (size_t)bb * NN * NN;
    const float* s2b = s2g + bb * NN;

    for (int j0 = 0; j0 < NN; j0 += 64) {
        // ---- stage WhT j-tile: 256 f x 64 k bf16, uint4 (8 bf16) each ----
#pragma unroll
        for (int it = 0; it < 8; ++it) {
            const int q = tid + it * 256;   // 0..2047
            const int f = q >> 3;           // 0..255
            const int kc = (q & 7) * 8;     // 0..56
            *(uint4*)&WhsT[f][kc] =
                *(const uint4*)&WhT[whtBase + (size_t)f * NN + j0 + kc];
        }
        // ---- P tile: 32 rows x 64 j, 2 adjacent j per thread x 4 iters ----
#pragma unroll
        for (int it = 0; it < 4; ++it) {
            const int q = tid + it * 256;    // 0..1023
            const int ir = q >> 5;           // 0..31 (same for 32-lane group)
            const int kp = (q & 31) * 2;     // 0..62
            const int j = j0 + kp;
            const int2 av = *(const int2*)&adj[adjBase + (size_t)(i0 + ir) * NN + j];
            const float2 s2v = *(const float2*)&s2b[j];
            const float s1v = s1_s[ir];
            float x0 = s1v + s2v.x;
            float x1 = s1v + s2v.y;
            x0 = x0 > 0.f ? x0 : ALPHA * x0;
            x1 = x1 > 0.f ? x1 : ALPHA * x1;
            const float p0 = av.x > 0 ? __expf(x0) : 0.f;
            const float p1 = av.y > 0 ? __expf(x1) : 0.f;
            const unsigned int pk =
                (unsigned int)f2bf(p0) | ((unsigned int)f2bf(p1) << 16);
            *(unsigned int*)&Pb[ir][kp] = pk;
            float ps = p0 + p1;
            ps += __shfl_xor(ps, 16);
            ps += __shfl_xor(ps, 8);
            ps += __shfl_xor(ps, 4);
            ps += __shfl_xor(ps, 2);
            ps += __shfl_xor(ps, 1);
            if ((tid & 31) == 0) l_s[ir] += ps;  // unique thread per ir
        }
        __syncthreads();
        // ---- MFMA: out[32 x 64f] += P[32 x 64k] * WhsT[64k x 64f] ----
        const int f0 = wave * 64;
#pragma unroll
        for (int k0 = 0; k0 < 64; k0 += 32) {
            bf16x8 af[2];
#pragma unroll
            for (int m = 0; m < 2; ++m)
                af[m] = *(const bf16x8*)&Pb[m * 16 + l16][k0 + quad * 8];
#pragma unroll
            for (int nf = 0; nf < 4; ++nf) {
                const bf16x8 bfr =
                    *(const bf16x8*)&WhsT[f0 + nf * 16 + l16][k0 + quad * 8];
#pragma unroll
                for (int m = 0; m < 2; ++m)
                    acc[m][nf] = __builtin_amdgcn_mfma_f32_16x16x32_bf16(
                        af[m], bfr, acc[m][nf], 0, 0, 0);
            }
        }
        __syncthreads();
    }

    // ---- epilogue: invert denominators once, then scale + store ----
    if (tid < 32) l_s[tid] = 1.0f / l_s[tid];
    __syncthreads();

    const int f0 = wave * 64;
#pragma unroll
    for (int m = 0; m < 2; ++m) {
#pragma unroll
        for (int r = 0; r < 4; ++r) {
            const int row = m * 16 + quad * 4 + r;
            const float inv = l_s[row];
#pragma unroll
            for (int nf = 0; nf < 4; ++nf) {
                out[((size_t)bb * NN + i0 + row) * NF + f0 + nf * 16 + l16] =
                    acc[m][nf][r] * inv;
            }
        }
    }
}

// ---------------------------------------------------------------------------
extern "C" void kernel_launch(void* const* d_in, const int* in_sizes, int n_in,
                              void* d_out, int out_size, void* d_ws, size_t ws_size,
                              hipStream_t stream) {
    const float* h = (const float*)d_in[0];
    const int* adj = (const int*)d_in[1];
    const float* W = (const float*)d_in[2];
    const float* a = (const float*)d_in[3];
    float* out = (float*)d_out;

    unsigned short* WhT = (unsigned short*)d_ws;  // 8.4 MB bf16, [b][f][n]
    float* s1 = (float*)((char*)d_ws + (size_t)NB * NN * NF * sizeof(unsigned short));
    float* s2 = s1 + (size_t)NB * NN;

    k_wh<<<dim3((NB * NN / 64) * (NF / 64)), dim3(256), 0, stream>>>(h, W, WhT);
    k_s12<<<dim3(NB * 8), dim3(256), 0, stream>>>(WhT, a, s1, s2);
    k_attn<<<dim3(NB * (NN / 32)), dim3(256), 0, stream>>>(WhT, adj, s1, s2, out);
}